// Round 20
// baseline (68.486 us; speedup 1.0000x reference)
//
#include <hip/hip_runtime.h>
#include <hip/hip_bf16.h>
#include <stdint.h>

#define BROWS 16384
#define DIM   256
#define BM    128               // A rows per block
#define NBM   (BROWS / BM)      // 128 row blocks
#define NBNR  16                // col-range blocks; each covers 1024 cols
#define NSTG  8                 // 128-col stages per block (16 KB each)
#define NCHUNK 64               // per-row partial chunks (16 bnr x 4 wc)

#define LOG2E 1.44269504088896340736f

typedef __attribute__((ext_vector_type(8)))  int   i32x8;
typedef __attribute__((ext_vector_type(16))) float f32x16;
typedef unsigned char uchar;

#if __has_builtin(__builtin_amdgcn_exp2f)
#define EXP2(x) __builtin_amdgcn_exp2f(x)   // bare v_exp_f32; |arg| small -> exact
#else
#define EXP2(x) exp2f(x)
#endif

__device__ __forceinline__ void gload_lds16(const void* g, void* l) {
  __builtin_amdgcn_global_load_lds(
      (const __attribute__((address_space(1))) void*)g,
      (__attribute__((address_space(3))) void*)l, 16, 0, 0);
}

// e2m1 RTN: grid {0,.5,1,1.5,2,3,4,6}, monotonic enc 0..7, sign = bit3.
__device__ __forceinline__ unsigned q4(float x) {
  float a = fabsf(x);
  unsigned q = (a >= 0.25f) + (a >= 0.75f) + (a >= 1.25f) + (a >= 1.75f) +
               (a >= 2.5f) + (a >= 3.5f) + (a >= 5.0f);
  return q | ((__float_as_uint(x) >> 28) & 8u);
}

// Tiled fp4 layout for 32x32x64 frags ("group-major"): row r, 16B K-chunk c
// (32 elems, c in 0..7): byte addr = (r>>5)*4096 + c*512 + (r&31)*16 + b.
// Wave frag for K-inst kt (lane l: row 32g+(l&31), chunk 2kt+(l>>5)) =
//   g*4096 + kt*1024 + l*16 -> 1KB contiguous, linear, conflict-free.

// ---------------- Kernel A: normalize BOTH matrices -> tiled fp4 + diag -----
// A = e2m1(x_hat * 16 * log2e), B = e2m1(x_hat * 16); MFMA E8M0 scales
// (2^-4 per side) undo the 16*16. dlog exact f32.
__global__ void normalize_both(const float* __restrict__ o,
                               const float* __restrict__ t,
                               uchar* __restrict__ o4,
                               uchar* __restrict__ t4,
                               float* __restrict__ dlog) {
  int row  = blockIdx.x * 4 + (threadIdx.x >> 6);
  int lane = threadIdx.x & 63;
  float4 a = *(reinterpret_cast<const float4*>(o + (size_t)row * DIM) + lane);
  float4 b = *(reinterpret_cast<const float4*>(t + (size_t)row * DIM) + lane);
  float sso = a.x * a.x + a.y * a.y + a.z * a.z + a.w * a.w;
  float sst = b.x * b.x + b.y * b.y + b.z * b.z + b.w * b.w;
  float d   = a.x * b.x + a.y * b.y + a.z * b.z + a.w * b.w;
#pragma unroll
  for (int m = 1; m < 64; m <<= 1) {
    sso += __shfl_xor(sso, m);
    sst += __shfl_xor(sst, m);
    d   += __shfl_xor(d, m);
  }
  float ro = rsqrtf(sso);
  float rt = rsqrtf(sst);
  if (lane == 0) dlog[row] = d * ro * rt;
  float qo = ro * (16.0f * LOG2E);   // A carries log2e
  float qt = rt * 16.0f;
  unsigned wo = q4(a.x * qo) | (q4(a.y * qo) << 4) |
                (q4(a.z * qo) << 8) | (q4(a.w * qo) << 12);
  unsigned wt = q4(b.x * qt) | (q4(b.y * qt) << 4) |
                (q4(b.z * qt) << 8) | (q4(b.w * qt) << 12);
  // lane's 4B word at row-byte lane*4 -> chunk c = lane>>2, b = (lane&3)*4
  size_t taddr = (size_t)(row >> 5) * 4096 + (size_t)((lane >> 2) * 512) +
                 (size_t)((row & 31) * 16) + (size_t)((lane & 3) * 4);
  *reinterpret_cast<unsigned*>(o4 + taddr) = wo;
  *reinterpret_cast<unsigned*>(t4 + taddr) = wt;
}

// ---------------- Kernel B: persistent-A fp4 32x32x64 GEMM, B via LDS -------
// Block = 128 A-rows x 1024 cols; 8 waves: wr = wid&1 (64-row strip = 2 row-
// tiles), wc = wid>>1 (32-col tile of each 128-col stage). 8 stages of 16 KB,
// double-buffered (32 KB LDS). vs r19: 32x32x64 halves MFMA count (64/wave,
// 9099 TF rate) and 2-row-tile reuse halves LDS reads (each B frag feeds 2
// MFMAs). Staging and frag reads both LINEAR (layout-native, no swizzle).
// mfma_scale_32x32x64 FP4 (cbsz=4, blgp=4), E8M0 scales 0x7B = 2^-4.
// A/B frag: lane l holds row/col (l&31), 32-elem K-chunk (l>>5) in dwords 0..3.
// C/D (m74/m101): col = lane&31, row = (reg&3) + 8*(reg>>2) + 4*(lane>>5).
__global__ __launch_bounds__(512, 4) void gemm_expsum(
    const uchar* __restrict__ A4,   // ohat fp4 tiled (x16*log2e)
    const uchar* __restrict__ B4,   // that fp4 tiled (x16)
    float* __restrict__ partial) {
  __shared__ __align__(16) uchar Bs[2][16384];  // 2 x 16 KB

  int b   = blockIdx.x;
  int xcd = b & 7;
  int idx = b >> 3;               // 0..255
  int bm  = xcd * 16 + (idx & 15);
  int bnr = idx >> 4;             // 0..15

  int tid  = threadIdx.x;
  int lane = tid & 63;
  int wid  = tid >> 6;            // 0..7
  int wr   = wid & 1;             // 64-row strip (2 row-groups)
  int wc   = wid >> 1;            // 32-col tile of each 128-col stage

  const uchar* Ap = A4 + (size_t)(bm * 4 + wr * 2) * 4096 + (size_t)lane * 16;
  const uchar* Bg = B4 + (size_t)bnr * 131072;   // 128 KB strip (1024 cols)

  // persistent A fragments: af[row-tile][kt], data in dwords 0..3
  i32x8 af[2][4];
#pragma unroll
  for (int rt = 0; rt < 2; ++rt)
#pragma unroll
    for (int kt = 0; kt < 4; ++kt) {
      int4 d = *reinterpret_cast<const int4*>(Ap + rt * 4096 + kt * 1024);
      af[rt][kt] = (i32x8){d.x, d.y, d.z, d.w, 0, 0, 0, 0};
    }

  float v[32];
#pragma unroll
  for (int j = 0; j < 32; ++j) v[j] = 0.f;

  const f32x16 zero16 = {0.f, 0.f, 0.f, 0.f, 0.f, 0.f, 0.f, 0.f,
                         0.f, 0.f, 0.f, 0.f, 0.f, 0.f, 0.f, 0.f};

  // stage st (16 KB = 128 cols = 4 groups): 2 x 16B gload/thread, linear.
#define STAGE(st, s)                                                           \
  {                                                                            \
    _Pragma("unroll") for (int p = 0; p < 2; ++p)                              \
        gload_lds16(Bg + (size_t)(st) * 16384 + p * 8192 + wid * 1024 +        \
                        lane * 16,                                             \
                    (char*)Bs[s] + p * 8192 + wid * 1024 + lane * 16);         \
  }

#define COMPUTE(s)                                                             \
  {                                                                            \
    const uchar* bb = Bs[s] + wc * 4096 + lane * 16;                           \
    f32x16 a0 = zero16, a1 = zero16;                                           \
    _Pragma("unroll") for (int kt = 0; kt < 4; ++kt) {                         \
      i32x8 bf = (i32x8){0, 0, 0, 0, 0, 0, 0, 0};                              \
      *reinterpret_cast<int4*>(&bf) =                                          \
          *reinterpret_cast<const int4*>(bb + kt * 1024);                      \
      a0 = __builtin_amdgcn_mfma_scale_f32_32x32x64_f8f6f4(                    \
          af[0][kt], bf, a0, 4, 4, 0, 0x7B7B7B7B, 0, 0x7B7B7B7B);              \
      a1 = __builtin_amdgcn_mfma_scale_f32_32x32x64_f8f6f4(                    \
          af[1][kt], bf, a1, 4, 4, 0, 0x7B7B7B7B, 0, 0x7B7B7B7B);              \
    }                                                                          \
    _Pragma("unroll") for (int r = 0; r < 16; ++r) {                           \
      v[r]      += EXP2(a0[r]);                                                \
      v[16 + r] += EXP2(a1[r]);                                                \
    }                                                                          \
  }

  STAGE(0, 0);
  __syncthreads();                 // stage 0 resident
#pragma unroll
  for (int st = 0; st < NSTG; ++st) {
    if (st < NSTG - 1) STAGE(st + 1, (st + 1) & 1);  // async into other buffer
    COMPUTE(st & 1);
    if (st < NSTG - 1) __syncthreads();  // drain stage(st+1); readers of st done
  }
#undef STAGE
#undef COMPUTE

  // ---- bisect butterfly: v[32] over the 32 fragment columns ----
  // 5 stages; lane ends with the full 32-col sum of entry j = lane&31
  // (same schema as the r12-verified 16-wide version, one extra stage).
#pragma unroll
  for (int s = 0; s < 5; ++s) {
    const int len = 32 >> s;
    const int bit = (lane >> s) & 1;
#pragma unroll
    for (int t = 0; t < 16; ++t) {
      if (t < (len >> 1)) {
        float a = v[2 * t], b2 = v[2 * t + 1];
        float recv = __shfl_xor(bit ? a : b2, 1 << s);
        v[t] = (bit ? b2 : a) + recv;
      }
    }
  }
  {
    int j   = lane & 31;           // rt = j>>4, reg = j&15
    int reg = j & 15;
    int row = bm * BM + wr * 64 + (j >> 4) * 32 +
              (reg & 3) + 8 * (reg >> 2) + 4 * (lane >> 5);
    partial[(size_t)row * NCHUNK + ((bnr << 2) | wc)] = v[0];
  }
}

// ---------------- Kernel C: per-row finish: log(sum) - exact diag ----------
// one thread per row: 64 partials = 16 x float4.
__global__ void row_finish(const float* __restrict__ partial,
                           const float* __restrict__ dlog,
                           float* __restrict__ rowloss) {
  int row = blockIdx.x * 256 + threadIdx.x;
  const float4* p = reinterpret_cast<const float4*>(partial + (size_t)row * NCHUNK);
  float s = 0.f;
#pragma unroll
  for (int q = 0; q < 16; ++q) {
    float4 pq = p[q];
    s += (pq.x + pq.y) + (pq.z + pq.w);
  }
  rowloss[row] = logf(s) - dlog[row];
}

// ---------------- Kernel D: mean over rows -> d_out[0] ----------------
__global__ void final_reduce(const float* __restrict__ rl, float* __restrict__ out) {
  __shared__ float sm[16];
  float s = 0.f;
  for (int i = threadIdx.x; i < BROWS; i += 1024) s += rl[i];
#pragma unroll
  for (int m = 1; m < 64; m <<= 1) s += __shfl_xor(s, m);
  int wid = threadIdx.x >> 6, lane = threadIdx.x & 63;
  if (lane == 0) sm[wid] = s;
  __syncthreads();
  if (wid == 0) {
    float v = (lane < 16) ? sm[lane] : 0.f;
#pragma unroll
    for (int m = 1; m < 16; m <<= 1) v += __shfl_xor(v, m);
    if (lane == 0) out[0] = v / (float)BROWS;
  }
}

extern "C" void kernel_launch(void* const* d_in, const int* in_sizes, int n_in,
                              void* d_out, int out_size, void* d_ws, size_t ws_size,
                              hipStream_t stream) {
  const float* outputs = (const float*)d_in[0];
  const float* targets = (const float*)d_in[1];
  float* out = (float*)d_out;
  char* ws = (char*)d_ws;

  uchar* o4      = (uchar*)ws;                                      // 2 MB (tiled fp4)
  uchar* t4      = (uchar*)(ws + (size_t)2 * 1024 * 1024);          // 2 MB (tiled fp4)
  float* partial = (float*)(ws + (size_t)4 * 1024 * 1024);          // 4 MB
  float* dlog    = (float*)(ws + (size_t)8 * 1024 * 1024);          // 64 KB
  float* rowloss = (float*)(ws + (size_t)8 * 1024 * 1024 + 65536);  // 64 KB

  normalize_both<<<BROWS / 4, 256, 0, stream>>>(outputs, targets, o4, t4, dlog);
  gemm_expsum<<<NBM * NBNR, 512, 0, stream>>>(o4, t4, partial);
  row_finish<<<BROWS / 256, 256, 0, stream>>>(partial, dlog, rowloss);
  final_reduce<<<1, 1024, 0, stream>>>(rowloss, out);
}